// Round 5
// baseline (694.275 us; speedup 1.0000x reference)
//
#include <hip/hip_runtime.h>
#include <cstdint>
#include <cstddef>

// ---- fixed problem shape ----
constexpr int kB    = 4;
constexpr int kL    = 2048;
constexpr int kH    = 32;
constexpr int kP    = 64;
constexpr int kN    = 32;
constexpr int kD    = 2048;      // d_model
constexpr int kProjW = 4192;
constexpr int kLdp  = 4224;      // padded proj width (projh stride) = 33*128
constexpr int kM    = kB * kL;   // 8192
constexpr int kK    = kD;        // 2048
constexpr int kLC   = 64;        // scan chunk length
constexpr int kNC   = kL / kLC;  // 32

typedef _Float16 f16x8 __attribute__((ext_vector_type(8)));
typedef float f32x4 __attribute__((ext_vector_type(4)));

__device__ __forceinline__ float lane_bcast(float v, int lane) {
    return __int_as_float(__builtin_amdgcn_readlane(__float_as_int(v), lane));
}
__device__ __forceinline__ float silu_f(float x) { return x / (1.f + __expf(-x)); }

__device__ __forceinline__ void async_copy16(const void* g, void* lds) {
    __builtin_amdgcn_global_load_lds(
        (const __attribute__((address_space(1))) unsigned int*)(uintptr_t)g,
        (__attribute__((address_space(3))) unsigned int*)(uintptr_t)lds,
        16, 0, 0);
}

// ---------------- cast fp32 -> fp16 (8 elems/thread) ----------------
__global__ __launch_bounds__(256) void cast_f16_kernel(const float* __restrict__ in,
                                                       _Float16* __restrict__ out) {
    size_t i = ((size_t)blockIdx.x * 256 + threadIdx.x) * 8;
    float4 a = *(const float4*)(in + i);
    float4 b = *(const float4*)(in + i + 4);
    f16x8 o;
    o[0] = (_Float16)a.x; o[1] = (_Float16)a.y; o[2] = (_Float16)a.z; o[3] = (_Float16)a.w;
    o[4] = (_Float16)b.x; o[5] = (_Float16)b.y; o[6] = (_Float16)b.z; o[7] = (_Float16)b.w;
    *(f16x8*)(out + i) = o;
}

// ------------- transpose + cast: W (R x C fp32) -> Wt (Cpad x R f16), zero pad -------------
__global__ __launch_bounds__(256) void transpose_cast_kernel(const float* __restrict__ W,
                                                             _Float16* __restrict__ Wt,
                                                             int R, int C) {
    __shared__ float tile[32][33];
    const int c0 = blockIdx.x * 32;
    const int r0 = blockIdx.y * 32;
    const int tx = threadIdx.x & 31;
    const int ty = threadIdx.x >> 5;   // 0..7
    #pragma unroll
    for (int i = 0; i < 32; i += 8) {
        int rr = r0 + ty + i;
        int cc = c0 + tx;
        tile[ty + i][tx] = (cc < C) ? W[(size_t)rr * C + cc] : 0.f;
    }
    __syncthreads();
    #pragma unroll
    for (int i = 0; i < 32; i += 8) {
        int cc = c0 + ty + i;          // row in Wt
        int rr = r0 + tx;              // col in Wt
        Wt[(size_t)cc * R + rr] = (_Float16)tile[tx][ty + i];
    }
}

// ---------------- GEMM: C[M x N] = A[M x K] * Bt[N x K]^T (+bias) ----------------
// 128x256 tile, BK=32, 256 threads (4 waves = 2M x 2N, 64x128 out per wave),
// 16x16x32 f16 MFMA, TRIPLE-buffered LDS (3 x 24 KB = 72 KB/block) so that
// TWO INDEPENDENT BLOCKS co-reside per CU (144 KB LDS, VGPR <= 256 via
// __launch_bounds__(256,2)). Blocks never share barriers -> when one block
// is in its LDS-read/wait phase the other issues MFMA: structural overlap
// of the LDS and matrix pipes that intra-block scheduling (r4 stagger,
// regressed) could not achieve.
// Per K-tile kt (buf = kt%3): {STAGE kt+2 -> buf[(kt+2)%3] (6 instrs);
//   12 ds_read_b128 (A 4, B 8); lgkm(0)+sched_barrier; setprio(1);
//   32 independent MFMA; setprio(0); vmcnt(6) [0 at tail]; barrier}.
// vmcnt(6): outstanding = kt+1's 6 + kt+2's 6; retires kt+1 exactly, kt+2
// stays in flight (never drain-0 mid-loop; ~1.5 tiles of HBM slack).
// Race-safety: buf[(kt+2)%3] readers ran in kt-1, retired at their lgkm(0)
// before kt-1's closing barrier; reads of buf[kt%3] confirmed by end-of-
// (kt-1) vmcnt+barrier. LDS lane-linear (conflict-free): A sub-tile i
// (16 rows) at byte i*1024 + lane*16; B sub-tile j at 8192 + j*1024 + lane*16.
// XCD swizzle: bijective (nwg%8==0), each XCD owns a contiguous wg chunk.
template <bool OUT_F16>
__global__ __launch_bounds__(256, 2) void gemm128_kernel(
    const _Float16* __restrict__ A, const _Float16* __restrict__ Bt,
    const float* __restrict__ bias,
    void* __restrict__ Cout, int K, int ldc, int nn)
{
    __shared__ __attribute__((aligned(16))) _Float16 lds[3 * 12288]; // 72 KiB

    const int tid = threadIdx.x;
    const int l = tid & 63, r = l & 15, q = l >> 4;
    const int w = tid >> 6, wm = w >> 1, wn = w & 1;

    // bijective XCD-aware swizzle
    const int nwg = gridDim.x;
    const int q8 = nwg >> 3;
    const int pid = blockIdx.x;
    const int wg = (pid & 7) * q8 + (pid >> 3);
    const int m_idx = wg / nn;
    const int n_idx = wg - m_idx * nn;
    const size_t tileM = (size_t)m_idx * 128;
    const size_t tileN = (size_t)n_idx * 256;

    // staging: thread t loads 16B from row sR (+64 per extra copy), k-col sC
    const int sR = ((tid >> 6) << 4) | (tid & 15);   // 0..63
    const int sC = ((tid >> 4) & 3) << 3;            // 0,8,16,24
    const _Float16* aSrc = A  + (tileM + sR) * (size_t)K + sC;
    const _Float16* bSrc = Bt + (tileN + sR) * (size_t)K + sC;
    _Float16* dst0 = lds + tid * 8;

    auto STAGE = [&](int buf, int kt2) {
        const _Float16* a = aSrc + kt2 * 32;
        const _Float16* b = bSrc + kt2 * 32;
        _Float16* d = dst0 + buf * 12288;
        async_copy16(a, d);                           // A rows 0-63
        async_copy16(a + (size_t)64 * K, d + 2048);   // A rows 64-127
        #pragma unroll
        for (int c = 0; c < 4; ++c)                   // B rows c*64 .. +63
            async_copy16(b + (size_t)(c * 64) * K, d + 4096 + c * 2048);
    };

    const int NT = K >> 5;   // 64
    STAGE(0, 0); STAGE(1, 1);
    asm volatile("s_waitcnt vmcnt(6)" ::: "memory");  // tile0 landed
    asm volatile("s_barrier" ::: "memory");

    f32x4 acc[4][8] = {};
    f16x8 af[4], bf[8];

    const int aRd = wm * 4096 + l * 16;          // byte offset of wave's A sub-tiles
    const int bRd = 8192 + wn * 8192 + l * 16;   // byte offset of wave's B sub-tiles

    int cs = 0;
    for (int kt = 0; kt < NT; ++kt) {
        const char* base = (const char*)lds + cs * 24576;
        if (kt + 2 < NT) {
            int ns = cs + 2; if (ns >= 3) ns -= 3;
            STAGE(ns, kt + 2);
        }
        #pragma unroll
        for (int i = 0; i < 4; ++i)
            af[i] = *(const f16x8*)(base + aRd + i * 1024);
        #pragma unroll
        for (int j = 0; j < 8; ++j)
            bf[j] = *(const f16x8*)(base + bRd + j * 1024);
        asm volatile("s_waitcnt lgkmcnt(0)" ::: "memory");
        __builtin_amdgcn_sched_barrier(0);
        __builtin_amdgcn_s_setprio(1);
        #pragma unroll
        for (int i = 0; i < 4; ++i)
            #pragma unroll
            for (int j = 0; j < 8; ++j)
                acc[i][j] = __builtin_amdgcn_mfma_f32_16x16x32_f16(af[i], bf[j], acc[i][j], 0, 0, 0);
        __builtin_amdgcn_s_setprio(0);
        if (kt + 2 < NT) asm volatile("s_waitcnt vmcnt(6)" ::: "memory");  // kt+1 landed
        else             asm volatile("s_waitcnt vmcnt(0)" ::: "memory");  // tail drain
        asm volatile("s_barrier" ::: "memory");
        cs = (cs + 1 >= 3) ? 0 : cs + 1;
    }

    // ---- epilogue: C/D layout col=lane&15, row=(lane>>4)*4+u ----
    #pragma unroll
    for (int j = 0; j < 8; ++j) {
        const int col = (int)tileN + wn * 128 + j * 16 + r;
        float bv = 0.f;
        if (bias != nullptr) bv = bias[col];
        #pragma unroll
        for (int i = 0; i < 4; ++i) {
            const size_t row = tileM + (size_t)(wm * 64 + i * 16 + q * 4);
            #pragma unroll
            for (int u = 0; u < 4; ++u) {
                float v = acc[i][j][u] + bv;
                if (OUT_F16) ((_Float16*)Cout)[(row + u) * (size_t)ldc + col] = (_Float16)v;
                else         ((float*)Cout)[(row + u) * (size_t)ldc + col] = v;
            }
        }
    }
}

// ------------- skinny GEMM tail: cols [4096,4224) of proj, + dt/dA fused -------------
// C[M x 128] = A[M x K] * Bt[128 x K]^T + bias. Tile 32x128, 256 blocks,
// 256 threads (4 waves, wave w owns cols w*32..w*32+31). Double-buffered LDS
// (A 4KB + B 16KB per buf), stage 2 tiles ahead, 2 barriers/tile.
// dt cols (offset 64..95): epilogue computes softplus/exp -> dtv/dAv directly.
__global__ __launch_bounds__(256) void gemm_tail_kernel(
    const _Float16* __restrict__ A, const _Float16* __restrict__ Bt,
    const float* __restrict__ bias /*96 valid*/, _Float16* __restrict__ Cout,
    const float* __restrict__ A_log, const float* __restrict__ dt_bias,
    float* __restrict__ dtv, float* __restrict__ dAv)
{
    __shared__ __attribute__((aligned(16))) _Float16 lds[2 * 10240]; // 40 KiB
    const int K = kK;
    const int tid = threadIdx.x;
    const int l = tid & 63, r = l & 15, q = l >> 4;
    const int w = tid >> 6;
    const size_t tileM = (size_t)blockIdx.x * 32;

    const int sRa = ((tid >> 7) << 4) | (tid & 15);   // 0..31
    const int sC  = ((tid >> 4) & 7) << 3;
    const _Float16* aSrc = A + (tileM + sRa) * (size_t)K + sC;
    const _Float16* bSrc = Bt + (size_t)sRa * K + sC;
    _Float16* dst0 = lds + tid * 8;

    auto STG = [&](int buf, int kt2) {
        const _Float16* a = aSrc + kt2 * 64;
        const _Float16* b = bSrc + kt2 * 64;
        _Float16* d = dst0 + buf * 10240;
        async_copy16(a, d);                                    // A part (4 KB)
        #pragma unroll
        for (int c = 0; c < 4; ++c)
            async_copy16(b + (size_t)(c * 32) * K, d + 2048 + c * 2048);  // B part (16 KB)
    };

    const int NT = K / 64;   // 32
    STG(0, 0); STG(1, 1);
    asm volatile("s_waitcnt vmcnt(5)" ::: "memory");
    asm volatile("s_barrier" ::: "memory");

    f32x4 acc[2][2] = {};
    f16x8 af[2][2], bf[2][2];
    const int aRdT = l * 16;
    const int bRdT = 4096 + w * 2 * 2048 + l * 16;

    for (int kt = 0; kt < NT; ++kt) {
        const char* base = (const char*)lds + (kt & 1) * 20480;
        af[0][0] = *(const f16x8*)(base + aRdT);
        af[1][0] = *(const f16x8*)(base + aRdT + 2048);
        af[0][1] = *(const f16x8*)(base + aRdT + 1024);
        af[1][1] = *(const f16x8*)(base + aRdT + 3072);
        bf[0][0] = *(const f16x8*)(base + bRdT);
        bf[1][0] = *(const f16x8*)(base + bRdT + 2048);
        bf[0][1] = *(const f16x8*)(base + bRdT + 1024);
        bf[1][1] = *(const f16x8*)(base + bRdT + 3072);
        asm volatile("s_waitcnt lgkmcnt(0)" ::: "memory");
        __builtin_amdgcn_sched_barrier(0);
        asm volatile("s_barrier" ::: "memory");     // all waves' reads done
        if (kt + 2 < NT) STG(kt & 1, kt + 2);
        #pragma unroll
        for (int kk = 0; kk < 2; ++kk)
            #pragma unroll
            for (int i = 0; i < 2; ++i)
                #pragma unroll
                for (int j = 0; j < 2; ++j)
                    acc[i][j] = __builtin_amdgcn_mfma_f32_16x16x32_f16(af[i][kk], bf[j][kk], acc[i][j], 0, 0, 0);
        if (kt + 2 < NT) asm volatile("s_waitcnt vmcnt(5)" ::: "memory");
        else             asm volatile("s_waitcnt vmcnt(0)" ::: "memory");
        asm volatile("s_barrier" ::: "memory");
    }

    // epilogue: col offset = w*32 + j*16 + r in [0,128); dt block = [64,96)
    #pragma unroll
    for (int j = 0; j < 2; ++j) {
        const int colOff = w * 32 + j * 16 + r;
        const float bv = (colOff < 96) ? bias[colOff] : 0.f;
        #pragma unroll
        for (int i = 0; i < 2; ++i) {
            #pragma unroll
            for (int u = 0; u < 4; ++u) {
                const size_t row = tileM + (size_t)(i * 16 + q * 4 + u);
                float v = acc[i][j][u] + bv;
                Cout[row * kLdp + 4096 + colOff] = (_Float16)v;
            }
        }
        if (colOff >= 64 && colOff < 96) {
            const int h = colOff - 64;
            const float db = dt_bias[h];
            const float nA = -expf(A_log[h]);
            #pragma unroll
            for (int i = 0; i < 2; ++i) {
                #pragma unroll
                for (int u = 0; u < 4; ++u) {
                    const size_t row = tileM + (size_t)(i * 16 + q * 4 + u);
                    const int b = (int)(row >> 11), t = (int)(row & 2047);
                    float z = acc[i][j][u] + bv + db;
                    float dt = (z > 20.f) ? z : log1pf(expf(z));
                    float dA = expf(dt * nA);
                    const size_t idx = (((size_t)b * kH + h) << 11) | t;
                    dtv[idx] = dt;
                    dAv[idx] = dA;
                }
            }
        }
    }
}

// ---------------- scan pass 1: per-chunk local states (zero init) + decay product --------
__global__ __launch_bounds__(64) void scan_pass1_kernel(
    const _Float16* __restrict__ projh, const float* __restrict__ conv_w,
    const float* __restrict__ conv_b, const float* __restrict__ dtv,
    const float* __restrict__ dAv, float* __restrict__ cstate, float* __restrict__ Pch)
{
    const int blk = blockIdx.x;
    const int c   = blk & (kNC - 1);
    const int bh  = blk >> 5;            // kNC = 32
    const int h   = bh & (kH - 1);
    const int b   = bh >> 5;
    const int l   = threadIdx.x;
    const int t0  = c * kLC;

    const int chx = h * kP + l;          // x conv channel
    const int chb = 2048 + (l & 31);     // B conv channel (duplicated over half-wave)
    const float xw0 = conv_w[chx*4+0], xw1 = conv_w[chx*4+1], xw2 = conv_w[chx*4+2], xw3 = conv_w[chx*4+3];
    const float xbb = conv_b[chx];
    const float bw0 = conv_w[chb*4+0], bw1 = conv_w[chb*4+1], bw2 = conv_w[chb*4+2], bw3 = conv_w[chb*4+3];
    const float bbb = conv_b[chb];

    const _Float16* pb = projh + (size_t)b * kL * kLdp;
    const int colx = 2048 + chx;
    const int colb = 2048 + chb;

    float xq0=0.f, xq1=0.f, xq2=0.f, bq0=0.f, bq1=0.f, bq2=0.f;
    if (c > 0) {
        xq0 = (float)pb[(size_t)(t0-3)*kLdp + colx];
        xq1 = (float)pb[(size_t)(t0-2)*kLdp + colx];
        xq2 = (float)pb[(size_t)(t0-1)*kLdp + colx];
        bq0 = (float)pb[(size_t)(t0-3)*kLdp + colb];
        bq1 = (float)pb[(size_t)(t0-2)*kLdp + colb];
        bq2 = (float)pb[(size_t)(t0-1)*kLdp + colb];
    }

    float hs[kN];
    #pragma unroll
    for (int n = 0; n < kN; ++n) hs[n] = 0.f;
    float Pp = 1.f;
    const float* dtp = dtv + (size_t)bh * kL;
    const float* dAp = dAv + (size_t)bh * kL;

    // rolling prefetch: values for t loaded one iteration ahead
    float xv = (float)pb[(size_t)t0 * kLdp + colx];
    float bv = (float)pb[(size_t)t0 * kLdp + colb];
    float dt = dtp[t0], dA = dAp[t0];

    #pragma unroll 1
    for (int t = t0; t < t0 + kLC; ++t) {
        float xn = 0.f, bn = 0.f, dtn = 0.f, dAn = 0.f;
        if (t + 1 < t0 + kLC) {
            const size_t ro2 = (size_t)(t + 1) * kLdp;
            xn = (float)pb[ro2 + colx];
            bn = (float)pb[ro2 + colb];
            dtn = dtp[t + 1]; dAn = dAp[t + 1];
        }
        float sx = silu_f(xbb + xw0*xq0 + xw1*xq1 + xw2*xq2 + xw3*xv);
        float sb = silu_f(bbb + bw0*bq0 + bw1*bq1 + bw2*bq2 + bw3*bv);
        xq0=xq1; xq1=xq2; xq2=xv;
        bq0=bq1; bq1=bq2; bq2=bv;
        float dtx = dt * sx;
        Pp *= dA;
        #pragma unroll
        for (int n = 0; n < kN; ++n)
            hs[n] = fmaf(dA, hs[n], dtx * lane_bcast(sb, n));
        xv = xn; bv = bn; dt = dtn; dA = dAn;
    }
    float* cs = cstate + (size_t)blk * (kP * kN) + l * kN;
    #pragma unroll
    for (int n = 0; n < kN; ++n) cs[n] = hs[n];
    if (l == 0) Pch[blk] = Pp;
}

// ---------------- scan pass 2: sequential chunk combine (in place -> initial states) -----
__global__ __launch_bounds__(256) void scan_pass2_kernel(float* __restrict__ cstate,
                                                         const float* __restrict__ Pch) {
    const int bh  = blockIdx.x;
    const int off = threadIdx.x * 8;
    float s[8];
    #pragma unroll
    for (int i = 0; i < 8; ++i) s[i] = 0.f;
    float* base = cstate + (size_t)bh * (kNC * kP * kN) + off;
    #pragma unroll 1
    for (int c = 0; c < kNC; ++c) {
        float* cs = base + c * (kP * kN);
        float Pp = Pch[bh * kNC + c];
        #pragma unroll
        for (int i = 0; i < 8; ++i) {
            float loc = cs[i];
            cs[i] = s[i];                 // state entering chunk c
            s[i] = fmaf(Pp, s[i], loc);   // state entering chunk c+1
        }
    }
}

// ---------------- scan pass 3: replay chunk from known init state, emit y ----------------
__global__ __launch_bounds__(64) void scan_pass3_kernel(
    const _Float16* __restrict__ projh, const float* __restrict__ conv_w,
    const float* __restrict__ conv_b, const float* __restrict__ dtv,
    const float* __restrict__ dAv, const float* __restrict__ cstate,
    const float* __restrict__ D_param, float* __restrict__ ypre)
{
    const int blk = blockIdx.x;
    const int c   = blk & (kNC - 1);
    const int bh  = blk >> 5;
    const int h   = bh & (kH - 1);
    const int b   = bh >> 5;
    const int l   = threadIdx.x;
    const int t0  = c * kLC;

    const int chx = h * kP + l;      // x conv channel
    const int chc = 2048 + l;        // lanes 0..31 -> B channels, 32..63 -> C channels
    const float xw0 = conv_w[chx*4+0], xw1 = conv_w[chx*4+1], xw2 = conv_w[chx*4+2], xw3 = conv_w[chx*4+3];
    const float xbb = conv_b[chx];
    const float cw0 = conv_w[chc*4+0], cw1 = conv_w[chc*4+1], cw2 = conv_w[chc*4+2], cw3 = conv_w[chc*4+3];
    const float cbb = conv_b[chc];

    const _Float16* pb = projh + (size_t)b * kL * kLdp;
    const int colx = 2048 + chx;
    const int colc = 2048 + chc;     // = 4096 + l

    float xq0=0.f, xq1=0.f, xq2=0.f, cq0=0.f, cq1=0.f, cq2=0.f;
    if (c > 0) {
        xq0 = (float)pb[(size_t)(t0-3)*kLdp + colx];
        xq1 = (float)pb[(size_t)(t0-2)*kLdp + colx];
        xq2 = (float)pb[(size_t)(t0-1)*kLdp + colx];
        cq0 = (float)pb[(size_t)(t0-3)*kLdp + colc];
        cq1 = (float)pb[(size_t)(t0-2)*kLdp + colc];
        cq2 = (float)pb[(size_t)(t0-1)*kLdp + colc];
    }

    float hs[kN];
    const float* cs = cstate + (size_t)blk * (kP * kN) + l * kN;
    #pragma unroll
    for (int n = 0; n < kN; ++n) hs[n] = cs[n];
    const float Dh = D_param[h];
    const float* dtp = dtv + (size_t)bh * kL;
    const float* dAp = dAv + (size_t)bh * kL;
    float* yo = ypre + (size_t)b * kL * kD + h * kP + l;

    float xv = (float)pb[(size_t)t0 * kLdp + colx];
    float cv = (float)pb[(size_t)t0 * kLdp + colc];
    float dt = dtp[t0], dA = dAp[t0];

    #pragma unroll 1
    for (int t = t0; t < t0 + kLC; ++t) {
        float xn = 0.f, cn2 = 0.f, dtn = 0.f, dAn = 0.f;
        if (t + 1 < t0 + kLC) {
            const size_t ro2 = (size_t)(t + 1) * kLdp;
            xn = (float)pb[ro2 + colx];
            cn2 = (float)pb[ro2 + colc];
            dtn = dtp[t + 1]; dAn = dAp[t + 1];
        }
        float sx = silu_f(xbb + xw0*xq0 + xw1*xq1 + xw2*xq2 + xw3*xv);
        float sc = silu_f(cbb + cw0*cq0 + cw1*cq1 + cw2*cq2 + cw3*cv);
        xq0=xq1; xq1=xq2; xq2=xv;
        cq0=cq1; cq1=cq2; cq2=cv;
        float dtx = dt * sx;
        float y0 = Dh * sx, y1 = 0.f;
        #pragma unroll
        for (int n = 0; n < kN; ++n) {
            float bn = lane_bcast(sc, n);
            float cn = lane_bcast(sc, n + 32);
            hs[n] = fmaf(dA, hs[n], dtx * bn);
            if (n & 1) y1 = fmaf(hs[n], cn, y1);
            else       y0 = fmaf(hs[n], cn, y0);
        }
        yo[(size_t)t * kD] = y0 + y1;
        xv = xn; cv = cn2; dt = dtn; dA = dAn;
    }
}

// ---------------- gated RMSNorm -> f16 ----------------
__global__ __launch_bounds__(256) void gated_norm_kernel(
    const float* __restrict__ ypre, const _Float16* __restrict__ projh,
    const float* __restrict__ norm_w, _Float16* __restrict__ yh)
{
    const int row = blockIdx.x;
    const int tid = threadIdx.x;
    const float* yr = ypre + (size_t)row * kD;
    const _Float16* gr = projh + (size_t)row * kLdp;   // gate = cols [0,2048)
    float v[8];
    float ss = 0.f;
    #pragma unroll
    for (int u = 0; u < 8; ++u) {
        int col = tid + u * 256;
        float g = (float)gr[col];
        float t = yr[col] * (g / (1.f + __expf(-g)));
        v[u] = t;
        ss = fmaf(t, t, ss);
    }
    #pragma unroll
    for (int off = 32; off > 0; off >>= 1) ss += __shfl_xor(ss, off, 64);
    __shared__ float red[4];
    if ((tid & 63) == 0) red[tid >> 6] = ss;
    __syncthreads();
    float tot = (red[0] + red[1]) + (red[2] + red[3]);
    float scl = rsqrtf(tot * (1.f / (float)kD) + 1e-6f);
    #pragma unroll
    for (int u = 0; u < 8; ++u) {
        int col = tid + u * 256;
        yh[(size_t)row * kD + col] = (_Float16)(v[u] * scl * norm_w[col]);
    }
}

// ---------------- launcher ----------------
extern "C" void kernel_launch(void* const* d_in, const int* in_sizes, int n_in,
                              void* d_out, int out_size, void* d_ws, size_t ws_size,
                              hipStream_t stream)
{
    (void)in_sizes; (void)n_in; (void)out_size; (void)ws_size;
    const float* x       = (const float*)d_in[0];
    const float* W_in    = (const float*)d_in[1];
    const float* b_in    = (const float*)d_in[2];
    const float* conv_w  = (const float*)d_in[3];
    const float* conv_b  = (const float*)d_in[4];
    const float* A_log   = (const float*)d_in[5];
    const float* dt_bias = (const float*)d_in[6];
    const float* D_param = (const float*)d_in[7];
    const float* norm_w  = (const float*)d_in[8];
    const float* W_out   = (const float*)d_in[9];
    float* out = (float*)d_out;

    char* p = (char*)d_ws;
    _Float16* projh = (_Float16*)p; p += (size_t)kM * kLdp * 2;     // 69.2 MB
    _Float16* xh    = (_Float16*)p; p += (size_t)kM * kD * 2;       // 32 MiB (xh -> cstate -> yh)
    _Float16* Wt    = (_Float16*)p; p += (size_t)kLdp * kK * 2;     // 17.3 MB
    _Float16* Wot   = (_Float16*)p; p += (size_t)kD * kK * 2;       //  8.4 MB
    float* dtv      = (float*)p;    p += (size_t)kB * kH * kL * 4;  //  1.0 MB
    float* dAv      = (float*)p;    p += (size_t)kB * kH * kL * 4;  //  1.0 MB
    float* Pch      = (float*)p;    p += (size_t)kB * kH * kNC * 4;
    // buffer lifetimes on the 32 MiB region: xh [cast..GEMM1b] ->
    // cstate [pass1..pass3] -> yh [gated_norm..GEMM2]; all disjoint.
    float* cstate = (float*)xh;
    _Float16* yh  = xh;
    float* ypre = out;            // d_out used as fp32 scratch, overwritten by GEMM2

    // 1. cast x -> f16
    cast_f16_kernel<<<(kM * kD) / (256 * 8), 256, 0, stream>>>(x, xh);
    // 2-3. transpose+cast weights to N x K (pad W_in cols 4192->4224 with zeros)
    transpose_cast_kernel<<<dim3(kLdp / 32, kK / 32), 256, 0, stream>>>(W_in, Wt, kK, kProjW);
    transpose_cast_kernel<<<dim3(kD / 32, kK / 32), 256, 0, stream>>>(W_out, Wot, kK, kD);
    // 4. GEMM1a: proj cols [0,4096) — 1024 blocks, 2-blocks/CU co-resident, 2 rounds
    gemm128_kernel<true><<<1024, 256, 0, stream>>>(
        xh, Wt, b_in, (void*)projh, kK, kLdp, 16);
    // 5. GEMM1b: proj cols [4096,4224) (B/C/dt), dt/dA fused into epilogue
    gemm_tail_kernel<<<kM / 32, 256, 0, stream>>>(
        xh, Wt + (size_t)4096 * kK, b_in + 4096, projh, A_log, dt_bias, dtv, dAv);
    // 6-8. chunked scan (conv fused), kLC=64 -> 4096 blocks (4 waves/SIMD)
    scan_pass1_kernel<<<kB * kH * kNC, 64, 0, stream>>>(projh, conv_w, conv_b, dtv, dAv, cstate, Pch);
    scan_pass2_kernel<<<kB * kH, 256, 0, stream>>>(cstate, Pch);
    scan_pass3_kernel<<<kB * kH * kNC, 64, 0, stream>>>(projh, conv_w, conv_b, dtv, dAv, cstate, D_param, ypre);
    // 9. gated RMSNorm -> f16
    gated_norm_kernel<<<kM, 256, 0, stream>>>(ypre, projh, norm_w, yh);
    // 10. GEMM2: out = y @ W_out (512 blocks = 1 co-resident round)
    gemm128_kernel<false><<<512, 256, 0, stream>>>(
        yh, Wot, nullptr, (void*)out, kK, kD, 8);
}

// Round 6
// 650.992 us; speedup vs baseline: 1.0665x; 1.0665x over previous
//
#include <hip/hip_runtime.h>
#include <cstdint>
#include <cstddef>

// ---- fixed problem shape ----
constexpr int kB    = 4;
constexpr int kL    = 2048;
constexpr int kH    = 32;
constexpr int kP    = 64;
constexpr int kN    = 32;
constexpr int kD    = 2048;      // d_model
constexpr int kProjW = 4192;
constexpr int kLdp  = 4224;      // padded proj width (projh stride) = 33*128
constexpr int kM    = kB * kL;   // 8192
constexpr int kK    = 2048;      // GEMM K (both GEMMs)
constexpr int kLC   = 64;        // scan chunk length
constexpr int kNC   = kL / kLC;  // 32

typedef _Float16 f16x8 __attribute__((ext_vector_type(8)));
typedef float f32x4 __attribute__((ext_vector_type(4)));

__device__ __forceinline__ float lane_bcast(float v, int lane) {
    return __int_as_float(__builtin_amdgcn_readlane(__float_as_int(v), lane));
}
__device__ __forceinline__ float silu_f(float x) { return x / (1.f + __expf(-x)); }

__device__ __forceinline__ void async_copy16(const void* g, void* lds) {
    __builtin_amdgcn_global_load_lds(
        (const __attribute__((address_space(1))) unsigned int*)(uintptr_t)g,
        (__attribute__((address_space(3))) unsigned int*)(uintptr_t)lds,
        16, 0, 0);
}

// ---------------- cast fp32 -> fp16 (8 elems/thread) ----------------
__global__ __launch_bounds__(256) void cast_f16_kernel(const float* __restrict__ in,
                                                       _Float16* __restrict__ out) {
    size_t i = ((size_t)blockIdx.x * 256 + threadIdx.x) * 8;
    float4 a = *(const float4*)(in + i);
    float4 b = *(const float4*)(in + i + 4);
    f16x8 o;
    o[0] = (_Float16)a.x; o[1] = (_Float16)a.y; o[2] = (_Float16)a.z; o[3] = (_Float16)a.w;
    o[4] = (_Float16)b.x; o[5] = (_Float16)b.y; o[6] = (_Float16)b.z; o[7] = (_Float16)b.w;
    *(f16x8*)(out + i) = o;
}

// ------------- transpose + cast: W (R x C fp32) -> Wt (Cpad x R f16), zero pad -------------
__global__ __launch_bounds__(256) void transpose_cast_kernel(const float* __restrict__ W,
                                                             _Float16* __restrict__ Wt,
                                                             int R, int C) {
    __shared__ float tile[32][33];
    const int c0 = blockIdx.x * 32;
    const int r0 = blockIdx.y * 32;
    const int tx = threadIdx.x & 31;
    const int ty = threadIdx.x >> 5;   // 0..7
    #pragma unroll
    for (int i = 0; i < 32; i += 8) {
        int rr = r0 + ty + i;
        int cc = c0 + tx;
        tile[ty + i][tx] = (cc < C) ? W[(size_t)rr * C + cc] : 0.f;
    }
    __syncthreads();
    #pragma unroll
    for (int i = 0; i < 32; i += 8) {
        int cc = c0 + ty + i;          // row in Wt
        int rr = r0 + tx;              // col in Wt
        Wt[(size_t)cc * R + rr] = (_Float16)tile[tx][ty + i];
    }
}

// ---------------- GEMM: C[M x N] = A[M x K] * Bt[N x K]^T (+bias) ----------------
// 256x256 tile, BK=32, 512 threads (8 waves = 2M x 4N; wave tile 128x64),
// 16x16x32 f16 MFMA, THREE LDS buffers (3 x 32 KB = 96 KB).
// Cross-boundary intra-wave pipeline: the 32 MFMA of tile kt are split into
// two 16-MFMA halves; the SECOND half executes at the top of tile kt+1,
// AFTER tile-(kt+1)'s 12 ds_reads have been issued — so read issue+drain
// hides under guaranteed-ready MFMA work instead of being exposed at every
// tile boundary (r3's 44% wait).
// Per tile kt: {vmcnt(4) [0 at kt=NT-1]; barrier; 12 ds_read of buf[kt%3];
//   stage(kt+2)->buf[(kt+2)%3] (4 gload_lds); SB; setprio(1);
//   16 MFMA 2nd-half(kt-1); lgkm(0)+SB; 16 MFMA 1st-half(kt); setprio(0)}.
// vmcnt ledger: at tile kt's wait, outstanding = stage(kt)?,stage(kt+1);
// vmcnt(4) retires stage(kt) exactly (stage(kt+1)'s 4 may remain). Tail:
// kt=NT-1 uses vmcnt(0). Stage race: buf[(kt+2)%3]'s readers = tile kt-1's
// reads, retired at each wave's lgkm(0) in kt-1, ordered before stage by
// barrier(kt). Frag liveness: af03 single set (dead after 1st-half, rewritten
// by next tile's reads); af47/bf double-buffered (live across boundary).
// LDS lane-linear (conflict-free): A frag g at byte g*1024 + lane*16; B frag
// at 16384 + g*1024 + lane*16. Stage thread t <-> (frag t>>6, lane t&63):
// src row = (t>>6)*16 + (t&15) [+128/instr], k-off = ((t>>4)&3)*8.
// XCD swizzle: bijective (nwg%8==0), each XCD owns a contiguous wg chunk.
template <bool OUT_F16>
__global__ __launch_bounds__(512, 2) void gemm256_kernel(
    const _Float16* __restrict__ A, const _Float16* __restrict__ Bt,
    const float* __restrict__ bias,
    void* __restrict__ Cout, int ldc, int nn)
{
    __shared__ __attribute__((aligned(16))) _Float16 lds[3 * 16384]; // 96 KiB

    const int tid = threadIdx.x;
    const int l = tid & 63, r = l & 15, q = l >> 4;
    const int w = tid >> 6, wm = w >> 2, wn = w & 3;

    // bijective XCD-aware swizzle: XCD x owns wg in [x*q8, (x+1)*q8)
    const int nwg = gridDim.x;
    const int q8 = nwg >> 3;
    const int pid = blockIdx.x;
    const int wg = (pid & 7) * q8 + (pid >> 3);
    const int m_idx = wg / nn;
    const int n_idx = wg - m_idx * nn;
    const size_t tileM = (size_t)m_idx * 256;
    const size_t tileN = (size_t)n_idx * 256;

    // staging source mapping (see header comment)
    const int sRow = ((tid >> 6) << 4) + (tid & 15);   // 0..127
    const int sCol = ((tid >> 4) & 3) << 3;            // 0,8,16,24
    const _Float16* aSrc = A  + (tileM + sRow) * (size_t)kK + sCol;
    const _Float16* bSrc = Bt + (tileN + sRow) * (size_t)kK + sCol;
    _Float16* dst0 = lds + tid * 8;

    auto STAGE = [&](int buf, int kt2) {
        const _Float16* a = aSrc + kt2 * 32;
        const _Float16* b = bSrc + kt2 * 32;
        _Float16* d = dst0 + buf * 16384;
        async_copy16(a, d);                              // A frags 0-7
        async_copy16(a + (size_t)128 * kK, d + 4096);    // A frags 8-15
        async_copy16(b, d + 8192);                       // B frags 0-7
        async_copy16(b + (size_t)128 * kK, d + 12288);   // B frags 8-15
    };

    constexpr int NT = kK / 32;   // 64
    const char* ldsb = (const char*)lds;
    const int aRd = wm * 8192 + l * 16;          // wave's A frags (8 x 1KB)
    const int bRd = wn * 4096 + l * 16;          // wave's B frags (4 x 1KB)

    f32x4 acc[8][4] = {};
    f16x8 af03[4], af47A[4], af47B[4], bfA[4], bfB[4];

#define MFMA_HALF(AFR, BFR, AO)                                                \
    _Pragma("unroll")                                                          \
    for (int i = 0; i < 4; ++i)                                                \
        _Pragma("unroll")                                                      \
        for (int j = 0; j < 4; ++j)                                            \
            acc[(AO) + i][j] = __builtin_amdgcn_mfma_f32_16x16x32_f16(         \
                AFR[i], BFR[j], acc[(AO) + i][j], 0, 0, 0);

#define TILE_BODY(KT, AF47_R, BF_R, AF47_P, BF_P, VM)                          \
    {                                                                          \
        asm volatile("s_waitcnt vmcnt(" #VM ")" ::: "memory");                 \
        asm volatile("s_barrier" ::: "memory");                                \
        const char* _bp = ldsb + ((KT) % 3) * 32768;                           \
        _Pragma("unroll")                                                      \
        for (int i = 0; i < 4; ++i)                                            \
            af03[i] = *(const f16x8*)(_bp + aRd + i * 1024);                   \
        _Pragma("unroll")                                                      \
        for (int i = 0; i < 4; ++i)                                            \
            AF47_R[i] = *(const f16x8*)(_bp + aRd + (4 + i) * 1024);           \
        _Pragma("unroll")                                                      \
        for (int j = 0; j < 4; ++j)                                            \
            BF_R[j] = *(const f16x8*)(_bp + 16384 + bRd + j * 1024);           \
        if ((KT) + 2 < NT) STAGE(((KT) + 2) % 3, (KT) + 2);                    \
        __builtin_amdgcn_sched_barrier(0);                                     \
        __builtin_amdgcn_s_setprio(1);                                         \
        MFMA_HALF(AF47_P, BF_P, 4)                                             \
        asm volatile("s_waitcnt lgkmcnt(0)" ::: "memory");                     \
        __builtin_amdgcn_sched_barrier(0);                                     \
        MFMA_HALF(af03, BF_R, 0)                                               \
        __builtin_amdgcn_s_setprio(0);                                         \
    }

    // prologue: stage tiles 0,1; confirm tile0; tile0 reads (set A) + 1st half
    STAGE(0, 0); STAGE(1, 1);
    asm volatile("s_waitcnt vmcnt(4)" ::: "memory");   // stage(0) landed
    asm volatile("s_barrier" ::: "memory");
    #pragma unroll
    for (int i = 0; i < 4; ++i) af03[i]  = *(const f16x8*)(ldsb + aRd + i * 1024);
    #pragma unroll
    for (int i = 0; i < 4; ++i) af47A[i] = *(const f16x8*)(ldsb + aRd + (4 + i) * 1024);
    #pragma unroll
    for (int j = 0; j < 4; ++j) bfA[j]   = *(const f16x8*)(ldsb + 16384 + bRd + j * 1024);
    STAGE(2, 2);
    asm volatile("s_waitcnt lgkmcnt(0)" ::: "memory");
    __builtin_amdgcn_sched_barrier(0);
    __builtin_amdgcn_s_setprio(1);
    MFMA_HALF(af03, bfA, 0)
    __builtin_amdgcn_s_setprio(0);

    for (int kt = 1; kt < NT - 1; kt += 2) {
        TILE_BODY(kt,     af47B, bfB, af47A, bfA, 4)
        TILE_BODY(kt + 1, af47A, bfA, af47B, bfB, 4)
    }
    TILE_BODY(NT - 1, af47B, bfB, af47A, bfA, 0)
    // epilogue MFMA: 2nd half of tile NT-1 (set B)
    __builtin_amdgcn_s_setprio(1);
    MFMA_HALF(af47B, bfB, 4)
    __builtin_amdgcn_s_setprio(0);
#undef MFMA_HALF
#undef TILE_BODY

    // ---- epilogue: C/D layout col=lane&15, row=(lane>>4)*4+u ----
    #pragma unroll
    for (int j = 0; j < 4; ++j) {
        const int col = (int)tileN + wn * 64 + j * 16 + r;
        float bv = 0.f;
        if (bias != nullptr) bv = bias[col];
        #pragma unroll
        for (int i = 0; i < 8; ++i) {
            const size_t row = tileM + (size_t)(wm * 128 + i * 16 + q * 4);
            #pragma unroll
            for (int u = 0; u < 4; ++u) {
                float v = acc[i][j][u] + bv;
                if (OUT_F16) ((_Float16*)Cout)[(row + u) * (size_t)ldc + col] = (_Float16)v;
                else         ((float*)Cout)[(row + u) * (size_t)ldc + col] = v;
            }
        }
    }
}

// ------------- skinny GEMM tail: cols [4096,4224) of proj, + dt/dA fused -------------
// C[M x 128] = A[M x K] * Bt[128 x K]^T + bias. Tile 32x128, 256 blocks,
// 256 threads (4 waves, wave w owns cols w*32..w*32+31). Double-buffered LDS
// (A 4KB + B 16KB per buf), stage 2 tiles ahead, 2 barriers/tile.
// dt cols (offset 64..95): epilogue computes softplus/exp -> dtv/dAv directly.
__global__ __launch_bounds__(256) void gemm_tail_kernel(
    const _Float16* __restrict__ A, const _Float16* __restrict__ Bt,
    const float* __restrict__ bias /*96 valid*/, _Float16* __restrict__ Cout,
    const float* __restrict__ A_log, const float* __restrict__ dt_bias,
    float* __restrict__ dtv, float* __restrict__ dAv)
{
    __shared__ __attribute__((aligned(16))) _Float16 lds[2 * 10240]; // 40 KiB
    const int K = kK;
    const int tid = threadIdx.x;
    const int l = tid & 63, r = l & 15, q = l >> 4;
    const int w = tid >> 6;
    const size_t tileM = (size_t)blockIdx.x * 32;

    const int sRa = ((tid >> 7) << 4) | (tid & 15);   // 0..31
    const int sC  = ((tid >> 4) & 7) << 3;
    const _Float16* aSrc = A + (tileM + sRa) * (size_t)K + sC;
    const _Float16* bSrc = Bt + (size_t)sRa * K + sC;
    _Float16* dst0 = lds + tid * 8;

    auto STG = [&](int buf, int kt2) {
        const _Float16* a = aSrc + kt2 * 64;
        const _Float16* b = bSrc + kt2 * 64;
        _Float16* d = dst0 + buf * 10240;
        async_copy16(a, d);                                    // A part (4 KB)
        #pragma unroll
        for (int c = 0; c < 4; ++c)
            async_copy16(b + (size_t)(c * 32) * K, d + 2048 + c * 2048);  // B part (16 KB)
    };

    const int NT = K / 64;   // 32
    STG(0, 0); STG(1, 1);
    asm volatile("s_waitcnt vmcnt(5)" ::: "memory");
    asm volatile("s_barrier" ::: "memory");

    f32x4 acc[2][2] = {};
    f16x8 af[2][2], bf[2][2];
    const int aRdT = l * 16;
    const int bRdT = 4096 + w * 2 * 2048 + l * 16;

    for (int kt = 0; kt < NT; ++kt) {
        const char* base = (const char*)lds + (kt & 1) * 20480;
        af[0][0] = *(const f16x8*)(base + aRdT);
        af[1][0] = *(const f16x8*)(base + aRdT + 2048);
        af[0][1] = *(const f16x8*)(base + aRdT + 1024);
        af[1][1] = *(const f16x8*)(base + aRdT + 3072);
        bf[0][0] = *(const f16x8*)(base + bRdT);
        bf[1][0] = *(const f16x8*)(base + bRdT + 2048);
        bf[0][1] = *(const f16x8*)(base + bRdT + 1024);
        bf[1][1] = *(const f16x8*)(base + bRdT + 3072);
        asm volatile("s_waitcnt lgkmcnt(0)" ::: "memory");
        __builtin_amdgcn_sched_barrier(0);
        asm volatile("s_barrier" ::: "memory");     // all waves' reads done
        if (kt + 2 < NT) STG(kt & 1, kt + 2);
        #pragma unroll
        for (int kk = 0; kk < 2; ++kk)
            #pragma unroll
            for (int i = 0; i < 2; ++i)
                #pragma unroll
                for (int j = 0; j < 2; ++j)
                    acc[i][j] = __builtin_amdgcn_mfma_f32_16x16x32_f16(af[i][kk], bf[j][kk], acc[i][j], 0, 0, 0);
        if (kt + 2 < NT) asm volatile("s_waitcnt vmcnt(5)" ::: "memory");
        else             asm volatile("s_waitcnt vmcnt(0)" ::: "memory");
        asm volatile("s_barrier" ::: "memory");
    }

    // epilogue: col offset = w*32 + j*16 + r in [0,128); dt block = [64,96)
    #pragma unroll
    for (int j = 0; j < 2; ++j) {
        const int colOff = w * 32 + j * 16 + r;
        const float bv = (colOff < 96) ? bias[colOff] : 0.f;
        #pragma unroll
        for (int i = 0; i < 2; ++i) {
            #pragma unroll
            for (int u = 0; u < 4; ++u) {
                const size_t row = tileM + (size_t)(i * 16 + q * 4 + u);
                float v = acc[i][j][u] + bv;
                Cout[row * kLdp + 4096 + colOff] = (_Float16)v;
            }
        }
        if (colOff >= 64 && colOff < 96) {
            const int h = colOff - 64;
            const float db = dt_bias[h];
            const float nA = -expf(A_log[h]);
            #pragma unroll
            for (int i = 0; i < 2; ++i) {
                #pragma unroll
                for (int u = 0; u < 4; ++u) {
                    const size_t row = tileM + (size_t)(i * 16 + q * 4 + u);
                    const int b = (int)(row >> 11), t = (int)(row & 2047);
                    float z = acc[i][j][u] + bv + db;
                    float dt = (z > 20.f) ? z : log1pf(expf(z));
                    float dA = expf(dt * nA);
                    const size_t idx = (((size_t)b * kH + h) << 11) | t;
                    dtv[idx] = dt;
                    dAv[idx] = dA;
                }
            }
        }
    }
}

// ---------------- scan pass 1: per-chunk local states (zero init) + decay product --------
__global__ __launch_bounds__(64) void scan_pass1_kernel(
    const _Float16* __restrict__ projh, const float* __restrict__ conv_w,
    const float* __restrict__ conv_b, const float* __restrict__ dtv,
    const float* __restrict__ dAv, float* __restrict__ cstate, float* __restrict__ Pch)
{
    const int blk = blockIdx.x;
    const int c   = blk & (kNC - 1);
    const int bh  = blk >> 5;            // kNC = 32
    const int h   = bh & (kH - 1);
    const int b   = bh >> 5;
    const int l   = threadIdx.x;
    const int t0  = c * kLC;

    const int chx = h * kP + l;          // x conv channel
    const int chb = 2048 + (l & 31);     // B conv channel (duplicated over half-wave)
    const float xw0 = conv_w[chx*4+0], xw1 = conv_w[chx*4+1], xw2 = conv_w[chx*4+2], xw3 = conv_w[chx*4+3];
    const float xbb = conv_b[chx];
    const float bw0 = conv_w[chb*4+0], bw1 = conv_w[chb*4+1], bw2 = conv_w[chb*4+2], bw3 = conv_w[chb*4+3];
    const float bbb = conv_b[chb];

    const _Float16* pb = projh + (size_t)b * kL * kLdp;
    const int colx = 2048 + chx;
    const int colb = 2048 + chb;

    float xq0=0.f, xq1=0.f, xq2=0.f, bq0=0.f, bq1=0.f, bq2=0.f;
    if (c > 0) {
        xq0 = (float)pb[(size_t)(t0-3)*kLdp + colx];
        xq1 = (float)pb[(size_t)(t0-2)*kLdp + colx];
        xq2 = (float)pb[(size_t)(t0-1)*kLdp + colx];
        bq0 = (float)pb[(size_t)(t0-3)*kLdp + colb];
        bq1 = (float)pb[(size_t)(t0-2)*kLdp + colb];
        bq2 = (float)pb[(size_t)(t0-1)*kLdp + colb];
    }

    float hs[kN];
    #pragma unroll
    for (int n = 0; n < kN; ++n) hs[n] = 0.f;
    float Pp = 1.f;
    const float* dtp = dtv + (size_t)bh * kL;
    const float* dAp = dAv + (size_t)bh * kL;

    // rolling prefetch: values for t loaded one iteration ahead
    float xv = (float)pb[(size_t)t0 * kLdp + colx];
    float bv = (float)pb[(size_t)t0 * kLdp + colb];
    float dt = dtp[t0], dA = dAp[t0];

    #pragma unroll 1
    for (int t = t0; t < t0 + kLC; ++t) {
        float xn = 0.f, bn = 0.f, dtn = 0.f, dAn = 0.f;
        if (t + 1 < t0 + kLC) {
            const size_t ro2 = (size_t)(t + 1) * kLdp;
            xn = (float)pb[ro2 + colx];
            bn = (float)pb[ro2 + colb];
            dtn = dtp[t + 1]; dAn = dAp[t + 1];
        }
        float sx = silu_f(xbb + xw0*xq0 + xw1*xq1 + xw2*xq2 + xw3*xv);
        float sb = silu_f(bbb + bw0*bq0 + bw1*bq1 + bw2*bq2 + bw3*bv);
        xq0=xq1; xq1=xq2; xq2=xv;
        bq0=bq1; bq1=bq2; bq2=bv;
        float dtx = dt * sx;
        Pp *= dA;
        #pragma unroll
        for (int n = 0; n < kN; ++n)
            hs[n] = fmaf(dA, hs[n], dtx * lane_bcast(sb, n));
        xv = xn; bv = bn; dt = dtn; dA = dAn;
    }
    float* cs = cstate + (size_t)blk * (kP * kN) + l * kN;
    #pragma unroll
    for (int n = 0; n < kN; ++n) cs[n] = hs[n];
    if (l == 0) Pch[blk] = Pp;
}

// ---------------- scan pass 2: sequential chunk combine (in place -> initial states) -----
__global__ __launch_bounds__(256) void scan_pass2_kernel(float* __restrict__ cstate,
                                                         const float* __restrict__ Pch) {
    const int bh  = blockIdx.x;
    const int off = threadIdx.x * 8;
    float s[8];
    #pragma unroll
    for (int i = 0; i < 8; ++i) s[i] = 0.f;
    float* base = cstate + (size_t)bh * (kNC * kP * kN) + off;
    #pragma unroll 1
    for (int c = 0; c < kNC; ++c) {
        float* cs = base + c * (kP * kN);
        float Pp = Pch[bh * kNC + c];
        #pragma unroll
        for (int i = 0; i < 8; ++i) {
            float loc = cs[i];
            cs[i] = s[i];                 // state entering chunk c
            s[i] = fmaf(Pp, s[i], loc);   // state entering chunk c+1
        }
    }
}

// ---------------- scan pass 3: replay chunk from known init state, emit y ----------------
__global__ __launch_bounds__(64) void scan_pass3_kernel(
    const _Float16* __restrict__ projh, const float* __restrict__ conv_w,
    const float* __restrict__ conv_b, const float* __restrict__ dtv,
    const float* __restrict__ dAv, const float* __restrict__ cstate,
    const float* __restrict__ D_param, float* __restrict__ ypre)
{
    const int blk = blockIdx.x;
    const int c   = blk & (kNC - 1);
    const int bh  = blk >> 5;
    const int h   = bh & (kH - 1);
    const int b   = bh >> 5;
    const int l   = threadIdx.x;
    const int t0  = c * kLC;

    const int chx = h * kP + l;      // x conv channel
    const int chc = 2048 + l;        // lanes 0..31 -> B channels, 32..63 -> C channels
    const float xw0 = conv_w[chx*4+0], xw1 = conv_w[chx*4+1], xw2 = conv_w[chx*4+2], xw3 = conv_w[chx*4+3];
    const float xbb = conv_b[chx];
    const float cw0 = conv_w[chc*4+0], cw1 = conv_w[chc*4+1], cw2 = conv_w[chc*4+2], cw3 = conv_w[chc*4+3];
    const float cbb = conv_b[chc];

    const _Float16* pb = projh + (size_t)b * kL * kLdp;
    const int colx = 2048 + chx;
    const int colc = 2048 + chc;     // = 4096 + l

    float xq0=0.f, xq1=0.f, xq2=0.f, cq0=0.f, cq1=0.f, cq2=0.f;
    if (c > 0) {
        xq0 = (float)pb[(size_t)(t0-3)*kLdp + colx];
        xq1 = (float)pb[(size_t)(t0-2)*kLdp + colx];
        xq2 = (float)pb[(size_t)(t0-1)*kLdp + colx];
        cq0 = (float)pb[(size_t)(t0-3)*kLdp + colc];
        cq1 = (float)pb[(size_t)(t0-2)*kLdp + colc];
        cq2 = (float)pb[(size_t)(t0-1)*kLdp + colc];
    }

    float hs[kN];
    const float* cs = cstate + (size_t)blk * (kP * kN) + l * kN;
    #pragma unroll
    for (int n = 0; n < kN; ++n) hs[n] = cs[n];
    const float Dh = D_param[h];
    const float* dtp = dtv + (size_t)bh * kL;
    const float* dAp = dAv + (size_t)bh * kL;
    float* yo = ypre + (size_t)b * kL * kD + h * kP + l;

    float xv = (float)pb[(size_t)t0 * kLdp + colx];
    float cv = (float)pb[(size_t)t0 * kLdp + colc];
    float dt = dtp[t0], dA = dAp[t0];

    #pragma unroll 1
    for (int t = t0; t < t0 + kLC; ++t) {
        float xn = 0.f, cn2 = 0.f, dtn = 0.f, dAn = 0.f;
        if (t + 1 < t0 + kLC) {
            const size_t ro2 = (size_t)(t + 1) * kLdp;
            xn = (float)pb[ro2 + colx];
            cn2 = (float)pb[ro2 + colc];
            dtn = dtp[t + 1]; dAn = dAp[t + 1];
        }
        float sx = silu_f(xbb + xw0*xq0 + xw1*xq1 + xw2*xq2 + xw3*xv);
        float sc = silu_f(cbb + cw0*cq0 + cw1*cq1 + cw2*cq2 + cw3*cv);
        xq0=xq1; xq1=xq2; xq2=xv;
        cq0=cq1; cq1=cq2; cq2=cv;
        float dtx = dt * sx;
        float y0 = Dh * sx, y1 = 0.f;
        #pragma unroll
        for (int n = 0; n < kN; ++n) {
            float bn = lane_bcast(sc, n);
            float cn = lane_bcast(sc, n + 32);
            hs[n] = fmaf(dA, hs[n], dtx * bn);
            if (n & 1) y1 = fmaf(hs[n], cn, y1);
            else       y0 = fmaf(hs[n], cn, y0);
        }
        yo[(size_t)t * kD] = y0 + y1;
        xv = xn; cv = cn2; dt = dtn; dA = dAn;
    }
}

// ---------------- gated RMSNorm -> f16 (vectorized: 8 contiguous per thread) ----------------
__global__ __launch_bounds__(256) void gated_norm_kernel(
    const float* __restrict__ ypre, const _Float16* __restrict__ projh,
    const float* __restrict__ norm_w, _Float16* __restrict__ yh)
{
    const int row = blockIdx.x;
    const int tid = threadIdx.x;
    const int c0 = tid * 8;
    const float* yr = ypre + (size_t)row * kD;
    const _Float16* gr = projh + (size_t)row * kLdp;   // gate = cols [0,2048)
    float4 ya = *(const float4*)(yr + c0);
    float4 yb = *(const float4*)(yr + c0 + 4);
    f16x8 g8 = *(const f16x8*)(gr + c0);
    float v[8];
    const float yv[8] = {ya.x, ya.y, ya.z, ya.w, yb.x, yb.y, yb.z, yb.w};
    float ss = 0.f;
    #pragma unroll
    for (int u = 0; u < 8; ++u) {
        float g = (float)g8[u];
        float t = yv[u] * (g / (1.f + __expf(-g)));
        v[u] = t;
        ss = fmaf(t, t, ss);
    }
    #pragma unroll
    for (int off = 32; off > 0; off >>= 1) ss += __shfl_xor(ss, off, 64);
    __shared__ float red[4];
    if ((tid & 63) == 0) red[tid >> 6] = ss;
    __syncthreads();
    float tot = (red[0] + red[1]) + (red[2] + red[3]);
    float scl = rsqrtf(tot * (1.f / (float)kD) + 1e-6f);
    float4 wa = *(const float4*)(norm_w + c0);
    float4 wb = *(const float4*)(norm_w + c0 + 4);
    const float wv[8] = {wa.x, wa.y, wa.z, wa.w, wb.x, wb.y, wb.z, wb.w};
    f16x8 o;
    #pragma unroll
    for (int u = 0; u < 8; ++u) o[u] = (_Float16)(v[u] * scl * wv[u]);
    *(f16x8*)(yh + (size_t)row * kD + c0) = o;
}

// ---------------- launcher ----------------
extern "C" void kernel_launch(void* const* d_in, const int* in_sizes, int n_in,
                              void* d_out, int out_size, void* d_ws, size_t ws_size,
                              hipStream_t stream)
{
    (void)in_sizes; (void)n_in; (void)out_size; (void)ws_size;
    const float* x       = (const float*)d_in[0];
    const float* W_in    = (const float*)d_in[1];
    const float* b_in    = (const float*)d_in[2];
    const float* conv_w  = (const float*)d_in[3];
    const float* conv_b  = (const float*)d_in[4];
    const float* A_log   = (const float*)d_in[5];
    const float* dt_bias = (const float*)d_in[6];
    const float* D_param = (const float*)d_in[7];
    const float* norm_w  = (const float*)d_in[8];
    const float* W_out   = (const float*)d_in[9];
    float* out = (float*)d_out;

    char* p = (char*)d_ws;
    _Float16* projh = (_Float16*)p; p += (size_t)kM * kLdp * 2;     // 69.2 MB
    _Float16* xh    = (_Float16*)p; p += (size_t)kM * kD * 2;       // 32 MiB (xh -> cstate -> yh)
    _Float16* Wt    = (_Float16*)p; p += (size_t)kLdp * kK * 2;     // 17.3 MB
    _Float16* Wot   = (_Float16*)p; p += (size_t)kD * kK * 2;       //  8.4 MB
    float* dtv      = (float*)p;    p += (size_t)kB * kH * kL * 4;  //  1.0 MB
    float* dAv      = (float*)p;    p += (size_t)kB * kH * kL * 4;  //  1.0 MB
    float* Pch      = (float*)p;    p += (size_t)kB * kH * kNC * 4;
    // buffer lifetimes on the 32 MiB region: xh [cast..GEMM1b] ->
    // cstate [pass1..pass3] -> yh [gated_norm..GEMM2]; all disjoint.
    float* cstate = (float*)xh;
    _Float16* yh  = xh;
    float* ypre = out;            // d_out used as fp32 scratch, overwritten by GEMM2

    // 1. cast x -> f16
    cast_f16_kernel<<<(kM * kD) / (256 * 8), 256, 0, stream>>>(x, xh);
    // 2-3. transpose+cast weights to N x K (pad W_in cols 4192->4224 with zeros)
    transpose_cast_kernel<<<dim3(kLdp / 32, kK / 32), 256, 0, stream>>>(W_in, Wt, kK, kProjW);
    transpose_cast_kernel<<<dim3(kD / 32, kK / 32), 256, 0, stream>>>(W_out, Wot, kK, kD);
    // 4. GEMM1a: proj cols [0,4096) — 512 blocks = exactly 2 resident rounds
    gemm256_kernel<true><<<512, 512, 0, stream>>>(
        xh, Wt, b_in, (void*)projh, kLdp, 16);
    // 5. GEMM1b: proj cols [4096,4224) (B/C/dt), dt/dA fused into epilogue
    gemm_tail_kernel<<<kM / 32, 256, 0, stream>>>(
        xh, Wt + (size_t)4096 * kK, b_in + 4096, projh, A_log, dt_bias, dtv, dAv);
    // 6-8. chunked scan (conv fused), kLC=64 -> 4096 blocks (4 waves/SIMD)
    scan_pass1_kernel<<<kB * kH * kNC, 64, 0, stream>>>(projh, conv_w, conv_b, dtv, dAv, cstate, Pch);
    scan_pass2_kernel<<<kB * kH, 256, 0, stream>>>(cstate, Pch);
    scan_pass3_kernel<<<kB * kH * kNC, 64, 0, stream>>>(projh, conv_w, conv_b, dtv, dAv, cstate, D_param, ypre);
    // 9. gated RMSNorm -> f16
    gated_norm_kernel<<<kM, 256, 0, stream>>>(ypre, projh, norm_w, yh);
    // 10. GEMM2: out = y @ W_out (256 blocks = exactly 1 resident round)
    gemm256_kernel<false><<<256, 512, 0, stream>>>(
        yh, Wot, nullptr, (void*)out, kD, 8);
}